// Round 1
// baseline (901.257 us; speedup 1.0000x reference)
//
#include <hip/hip_runtime.h>
#include <hip/hip_bf16.h>
#include <cmath>

#define N_TOK 16384
#define D_DIM 2048
#define H_DIM 1024
#define E_DIM 64

// ---------------------------------------------------------------------------
// GEMM1: h = x @ W1   [N,D] x [D,H] -> [N,H]  fp32
// 128x128 tile, BK=16, 256 threads, 8x8 micro-tile per thread.
// ---------------------------------------------------------------------------
__global__ __launch_bounds__(256) void gemm1_kernel(
    const float* __restrict__ x, const float* __restrict__ W1,
    float* __restrict__ h) {
  // As padded to 132 to break 4-way store conflicts (transpose store)
  __shared__ float As[16][132];
  __shared__ float Bs[16][128];
  const int t = threadIdx.x;
  const int bj = blockIdx.x;   // 0..7   (col tiles: 1024/128)
  const int bi = blockIdx.y;   // 0..127 (row tiles: 16384/128)
  const int row0 = bi * 128, col0 = bj * 128;
  const int ty = t >> 4, tx = t & 15;

  // A-load mapping: row ar (+64), k-quad ak
  const int ar = t >> 2;          // 0..63
  const int ak = (t & 3) * 4;     // 0,4,8,12
  // B-load mapping: k-row br (+8), col-quad bc
  const int br = t >> 5;          // 0..7
  const int bc = (t & 31) * 4;    // 0..124

  float acc[8][8];
#pragma unroll
  for (int i = 0; i < 8; i++)
#pragma unroll
    for (int j = 0; j < 8; j++) acc[i][j] = 0.f;

  const float* xA = x + (size_t)row0 * D_DIM;
  const float* wB = W1 + (size_t)col0;

  for (int k0 = 0; k0 < D_DIM; k0 += 16) {
    float4 a0 = *(const float4*)(xA + (size_t)ar * D_DIM + k0 + ak);
    float4 a1 = *(const float4*)(xA + (size_t)(ar + 64) * D_DIM + k0 + ak);
    float4 b0 = *(const float4*)(wB + (size_t)(k0 + br) * H_DIM + bc);
    float4 b1 = *(const float4*)(wB + (size_t)(k0 + br + 8) * H_DIM + bc);
    __syncthreads();
    As[ak + 0][ar] = a0.x;
    As[ak + 1][ar] = a0.y;
    As[ak + 2][ar] = a0.z;
    As[ak + 3][ar] = a0.w;
    As[ak + 0][ar + 64] = a1.x;
    As[ak + 1][ar + 64] = a1.y;
    As[ak + 2][ar + 64] = a1.z;
    As[ak + 3][ar + 64] = a1.w;
    *(float4*)&Bs[br][bc] = b0;
    *(float4*)&Bs[br + 8][bc] = b1;
    __syncthreads();
#pragma unroll
    for (int k = 0; k < 16; k++) {
      float a[8], b[8];
      *(float4*)&a[0] = *(const float4*)&As[k][ty * 8];
      *(float4*)&a[4] = *(const float4*)&As[k][ty * 8 + 4];
      *(float4*)&b[0] = *(const float4*)&Bs[k][tx * 8];
      *(float4*)&b[4] = *(const float4*)&Bs[k][tx * 8 + 4];
#pragma unroll
      for (int i = 0; i < 8; i++)
#pragma unroll
        for (int j = 0; j < 8; j++)
          acc[i][j] = fmaf(a[i], b[j], acc[i][j]);
    }
  }

#pragma unroll
  for (int i = 0; i < 8; i++) {
    float* hp = h + (size_t)(row0 + ty * 8 + i) * H_DIM + col0 + tx * 8;
    float4 v0 = make_float4(acc[i][0], acc[i][1], acc[i][2], acc[i][3]);
    float4 v1 = make_float4(acc[i][4], acc[i][5], acc[i][6], acc[i][7]);
    *(float4*)hp = v0;
    *(float4*)(hp + 4) = v1;
  }
}

// ---------------------------------------------------------------------------
// Kernel 2: per 8 tokens: +b1, LayerNorm, exact GELU, logits = g @ W2 + b2,
// softmax, top-2 (lax.top_k tie-break: lower index first), renorm weights.
// ---------------------------------------------------------------------------
__device__ __forceinline__ float gelu_exact(float v) {
  return 0.5f * v * (1.0f + erff(v * 0.70710678118654752f));
}

__global__ __launch_bounds__(256) void router_kernel(
    const float* __restrict__ hbuf, const float* __restrict__ b1,
    const float* __restrict__ gamma, const float* __restrict__ beta,
    const float* __restrict__ W2, const float* __restrict__ b2,
    float* __restrict__ out) {
  __shared__ float g[8][H_DIM];      // 32 KB post-GELU activations
  __shared__ float w2s[128][E_DIM];  // 32 KB W2 chunk
  __shared__ float lg[8][E_DIM];     // logits accumulators

  const int t = threadIdx.x;
  const int tok0 = blockIdx.x * 8;

  // ---- Phase 1: LayerNorm + GELU (32 lanes per token) ----
  const int tk = t >> 5;    // token 0..7
  const int l32 = t & 31;   // lane within 32-group
  float vals[32];
  {
    const float* hr = hbuf + (size_t)(tok0 + tk) * H_DIM;
    float s = 0.f, s2 = 0.f;
#pragma unroll
    for (int q = 0; q < 8; q++) {
      const int j = q * 128 + l32 * 4;
      float4 v = *(const float4*)(hr + j);
      float4 bb = *(const float4*)(b1 + j);
      v.x += bb.x; v.y += bb.y; v.z += bb.z; v.w += bb.w;
      vals[q * 4 + 0] = v.x; vals[q * 4 + 1] = v.y;
      vals[q * 4 + 2] = v.z; vals[q * 4 + 3] = v.w;
      s += v.x + v.y + v.z + v.w;
      s2 += v.x * v.x + v.y * v.y + v.z * v.z + v.w * v.w;
    }
#pragma unroll
    for (int off = 16; off; off >>= 1) {
      s += __shfl_xor(s, off, 32);
      s2 += __shfl_xor(s2, off, 32);
    }
    const float mean = s * (1.f / 1024.f);
    const float var = s2 * (1.f / 1024.f) - mean * mean;
    const float rstd = rsqrtf(var + 1e-5f);
#pragma unroll
    for (int q = 0; q < 8; q++) {
      const int j = q * 128 + l32 * 4;
      float4 gm = *(const float4*)(gamma + j);
      float4 bt = *(const float4*)(beta + j);
      float4 o;
      o.x = gelu_exact((vals[q * 4 + 0] - mean) * rstd * gm.x + bt.x);
      o.y = gelu_exact((vals[q * 4 + 1] - mean) * rstd * gm.y + bt.y);
      o.z = gelu_exact((vals[q * 4 + 2] - mean) * rstd * gm.z + bt.z);
      o.w = gelu_exact((vals[q * 4 + 3] - mean) * rstd * gm.w + bt.w);
      *(float4*)&g[tk][j] = o;
    }
  }

  // init logits with b2 (barrier inside chunk loop orders this before atomics)
  {
    float* lgf = &lg[0][0];
    lgf[t] = b2[t & 63];
    lgf[t + 256] = b2[t & 63];
  }

  // ---- Phase 2: logits = g @ W2 ----
  // thread covers 2 tokens x 4 experts, 4-way split over i (seg)
  const int seg = t >> 6;              // 0..3
  const int cell = t & 63;
  const int tp = cell >> 4;            // token pair: 2tp, 2tp+1
  const int e0 = (cell & 15) * 4;      // experts e0..e0+3

  float acc0[4] = {0.f, 0.f, 0.f, 0.f};
  float acc1[4] = {0.f, 0.f, 0.f, 0.f};

  for (int c = 0; c < 8; c++) {        // 8 chunks of 128 rows of W2
    __syncthreads();
#pragma unroll
    for (int q = 0; q < 8; q++) {
      const int idx = q * 1024 + t * 4;
      *(float4*)(&w2s[0][0] + idx) = *(const float4*)(W2 + c * 8192 + idx);
    }
    __syncthreads();
#pragma unroll
    for (int q = 0; q < 8; q++) {      // 32 i's per chunk, steps of 4
      const int i = seg * 32 + q * 4;
      float4 g0 = *(const float4*)&g[2 * tp][c * 128 + i];
      float4 g1 = *(const float4*)&g[2 * tp + 1][c * 128 + i];
      float4 w0 = *(const float4*)&w2s[i + 0][e0];
      float4 w1 = *(const float4*)&w2s[i + 1][e0];
      float4 w2v = *(const float4*)&w2s[i + 2][e0];
      float4 w3 = *(const float4*)&w2s[i + 3][e0];
      acc0[0] = fmaf(g0.x, w0.x, acc0[0]); acc0[1] = fmaf(g0.x, w0.y, acc0[1]);
      acc0[2] = fmaf(g0.x, w0.z, acc0[2]); acc0[3] = fmaf(g0.x, w0.w, acc0[3]);
      acc0[0] = fmaf(g0.y, w1.x, acc0[0]); acc0[1] = fmaf(g0.y, w1.y, acc0[1]);
      acc0[2] = fmaf(g0.y, w1.z, acc0[2]); acc0[3] = fmaf(g0.y, w1.w, acc0[3]);
      acc0[0] = fmaf(g0.z, w2v.x, acc0[0]); acc0[1] = fmaf(g0.z, w2v.y, acc0[1]);
      acc0[2] = fmaf(g0.z, w2v.z, acc0[2]); acc0[3] = fmaf(g0.z, w2v.w, acc0[3]);
      acc0[0] = fmaf(g0.w, w3.x, acc0[0]); acc0[1] = fmaf(g0.w, w3.y, acc0[1]);
      acc0[2] = fmaf(g0.w, w3.z, acc0[2]); acc0[3] = fmaf(g0.w, w3.w, acc0[3]);
      acc1[0] = fmaf(g1.x, w0.x, acc1[0]); acc1[1] = fmaf(g1.x, w0.y, acc1[1]);
      acc1[2] = fmaf(g1.x, w0.z, acc1[2]); acc1[3] = fmaf(g1.x, w0.w, acc1[3]);
      acc1[0] = fmaf(g1.y, w1.x, acc1[0]); acc1[1] = fmaf(g1.y, w1.y, acc1[1]);
      acc1[2] = fmaf(g1.y, w1.z, acc1[2]); acc1[3] = fmaf(g1.y, w1.w, acc1[3]);
      acc1[0] = fmaf(g1.z, w2v.x, acc1[0]); acc1[1] = fmaf(g1.z, w2v.y, acc1[1]);
      acc1[2] = fmaf(g1.z, w2v.z, acc1[2]); acc1[3] = fmaf(g1.z, w2v.w, acc1[3]);
      acc1[0] = fmaf(g1.w, w3.x, acc1[0]); acc1[1] = fmaf(g1.w, w3.y, acc1[1]);
      acc1[2] = fmaf(g1.w, w3.z, acc1[2]); acc1[3] = fmaf(g1.w, w3.w, acc1[3]);
    }
  }
#pragma unroll
  for (int j = 0; j < 4; j++) {
    atomicAdd(&lg[2 * tp][e0 + j], acc0[j]);
    atomicAdd(&lg[2 * tp + 1][e0 + j], acc1[j]);
  }
  __syncthreads();

  // ---- Phase 3: softmax + top-2 per token (one wave per 2 tokens) ----
  float* out_idx = out;                       // [N,2] as float
  float* out_w = out + 32768;                 // [N,2]
  float* out_logits = out + 65536;            // [N,64]

  const int wv = t >> 6;
  const int lane = t & 63;
#pragma unroll
  for (int tt = 0; tt < 2; tt++) {
    const int tok = wv * 2 + tt;
    const int n = tok0 + tok;
    const float L = lg[tok][lane];
    float m = L;
#pragma unroll
    for (int off = 32; off; off >>= 1) m = fmaxf(m, __shfl_xor(m, off));
    const float ex = expf(L - m);
    float sum = ex;
#pragma unroll
    for (int off = 32; off; off >>= 1) sum += __shfl_xor(sum, off);
    const float p = ex / sum;

    float v1 = p; int i1 = lane;
#pragma unroll
    for (int off = 32; off; off >>= 1) {
      float ov = __shfl_xor(v1, off);
      int oi = __shfl_xor(i1, off);
      if (ov > v1 || (ov == v1 && oi < i1)) { v1 = ov; i1 = oi; }
    }
    float v2 = (lane == i1) ? -1.f : p; int i2 = lane;
#pragma unroll
    for (int off = 32; off; off >>= 1) {
      float ov = __shfl_xor(v2, off);
      int oi = __shfl_xor(i2, off);
      if (ov > v2 || (ov == v2 && oi < i2)) { v2 = ov; i2 = oi; }
    }

    out_logits[(size_t)n * 64 + lane] = L;
    if (lane == 0) {
      const float dn = v1 + v2 + 1e-9f;
      out_idx[n * 2 + 0] = (float)i1;
      out_idx[n * 2 + 1] = (float)i2;
      out_w[n * 2 + 0] = v1 / dn;
      out_w[n * 2 + 1] = v2 / dn;
    }
  }
}

extern "C" void kernel_launch(void* const* d_in, const int* in_sizes, int n_in,
                              void* d_out, int out_size, void* d_ws, size_t ws_size,
                              hipStream_t stream) {
  const float* x = (const float*)d_in[0];
  const float* W1 = (const float*)d_in[1];
  const float* b1 = (const float*)d_in[2];
  const float* gamma = (const float*)d_in[3];
  const float* beta = (const float*)d_in[4];
  const float* W2 = (const float*)d_in[5];
  const float* b2 = (const float*)d_in[6];
  float* out = (float*)d_out;
  float* hbuf = (float*)d_ws;  // [N_TOK, H_DIM] fp32 = 64 MiB

  dim3 grid1(H_DIM / 128, N_TOK / 128);  // (8, 128)
  gemm1_kernel<<<grid1, 256, 0, stream>>>(x, W1, hbuf);

  router_kernel<<<N_TOK / 8, 256, 0, stream>>>(hbuf, b1, gamma, beta, W2, b2, out);
}

// Round 2
// 395.941 us; speedup vs baseline: 2.2762x; 2.2762x over previous
//
#include <hip/hip_runtime.h>
#include <hip/hip_bf16.h>
#include <cmath>

#define N_TOK 16384
#define D_DIM 2048
#define H_DIM 1024
#define E_DIM 64

typedef _Float16 half8 __attribute__((ext_vector_type(8)));
typedef float floatx4 __attribute__((ext_vector_type(4)));

#define GLOAD_LDS(gp, lp)                                                      \
  __builtin_amdgcn_global_load_lds(                                            \
      (const __attribute__((address_space(1))) unsigned int*)(gp),             \
      (__attribute__((address_space(3))) unsigned int*)(lp), 16, 0, 0)

// ---------------------------------------------------------------------------
// Split x (fp32) into hi/lo f16 arrays. 8 elems/thread.
// ---------------------------------------------------------------------------
__global__ __launch_bounds__(256) void split_x_kernel(
    const float* __restrict__ x, _Float16* __restrict__ xh,
    _Float16* __restrict__ xl) {
  size_t i = ((size_t)blockIdx.x * 256 + threadIdx.x) * 8;
  float4 v0 = *(const float4*)(x + i);
  float4 v1 = *(const float4*)(x + i + 4);
  float vs[8] = {v0.x, v0.y, v0.z, v0.w, v1.x, v1.y, v1.z, v1.w};
  half8 hh, ll;
#pragma unroll
  for (int j = 0; j < 8; j++) {
    _Float16 hv = (_Float16)vs[j];
    hh[j] = hv;
    ll[j] = (_Float16)(vs[j] - (float)hv);
  }
  *(half8*)(xh + i) = hh;
  *(half8*)(xl + i) = ll;
}

// ---------------------------------------------------------------------------
// Transpose + split W1 [2048k][1024c] -> whT/wlT [1024c][2048k] f16.
// ---------------------------------------------------------------------------
__global__ __launch_bounds__(256) void splitT_w1_kernel(
    const float* __restrict__ W1, _Float16* __restrict__ whT,
    _Float16* __restrict__ wlT) {
  __shared__ float ls[64][65];
  const int k0 = blockIdx.x * 64;  // 32
  const int c0 = blockIdx.y * 64;  // 16
  const int t = threadIdx.x;
  const int tr = t >> 6;   // 0..3
  const int tc = t & 63;
#pragma unroll
  for (int i = 0; i < 16; i++) {
    int k = tr * 16 + i;
    ls[k][tc] = W1[(size_t)(k0 + k) * H_DIM + c0 + tc];
  }
  __syncthreads();
#pragma unroll
  for (int i = 0; i < 16; i++) {
    int c = tr * 16 + i;
    float v = ls[tc][c];
    _Float16 hv = (_Float16)v;
    _Float16 lv = (_Float16)(v - (float)hv);
    whT[(size_t)(c0 + c) * D_DIM + k0 + tc] = hv;
    wlT[(size_t)(c0 + c) * D_DIM + k0 + tc] = lv;
  }
}

// ---------------------------------------------------------------------------
// GEMM1 via f16 split MFMA: h = (xh+xl) @ (wh+wl)^T  (3 products, fp32 acc)
// 128x128 tile, BK=32, 4 waves (2x2), each wave 64x64 = 4x4 frags 16x16x32.
// LDS linear [128 rows][32 k] f16 per tile; XOR slot-swizzle applied on the
// GLOBAL source (write side) + on ds_read addr (read side).
// ---------------------------------------------------------------------------
__global__ __launch_bounds__(256) void gemm1_mfma_kernel(
    const _Float16* __restrict__ xh, const _Float16* __restrict__ xl,
    const _Float16* __restrict__ whT, const _Float16* __restrict__ wlT,
    float* __restrict__ h) {
  __shared__ __align__(16) _Float16 Ah[128 * 32];
  __shared__ __align__(16) _Float16 Al[128 * 32];
  __shared__ __align__(16) _Float16 Bh[128 * 32];
  __shared__ __align__(16) _Float16 Bl[128 * 32];

  const int t = threadIdx.x;
  const int wave = t >> 6;
  const int lane = t & 63;
  const int bj = blockIdx.x;  // 0..7   col tiles
  const int bi = blockIdx.y;  // 0..127 row tiles
  const int row0 = bi * 128, col0 = bj * 128;
  const int wr = wave >> 1, wc = wave & 1;

  floatx4 acc[4][4];
#pragma unroll
  for (int m = 0; m < 4; m++)
#pragma unroll
    for (int n = 0; n < 4; n++) acc[m][n] = (floatx4){0.f, 0.f, 0.f, 0.f};

  // Staging descriptors (2 gload calls per tile per wave, 1 KB each).
  // Linear LDS byte o -> row o/64, slot (o/16)%4. Source slot = slot ^ swz(row).
  int ldsbase[2];
  size_t gaoff[2], gboff[2];
#pragma unroll
  for (int q = 0; q < 2; q++) {
    int o = wave * 2048 + q * 1024 + lane * 16;
    int row = o >> 6;
    int ss = ((o >> 4) & 3) ^ ((row >> 1) & 3);
    ldsbase[q] = wave * 2048 + q * 1024;
    gaoff[q] = (size_t)(row0 + row) * D_DIM + ss * 8;
    gboff[q] = (size_t)(col0 + row) * D_DIM + ss * 8;
  }

  // Fragment ds_read addresses (bytes within tile), swizzled to match.
  const int kg = lane >> 4;
  int aaddr[4], baddr[4];
#pragma unroll
  for (int m = 0; m < 4; m++) {
    int r = wr * 64 + m * 16 + (lane & 15);
    aaddr[m] = r * 64 + ((kg ^ ((r >> 1) & 3)) << 4);
    int c = wc * 64 + m * 16 + (lane & 15);
    baddr[m] = c * 64 + ((kg ^ ((c >> 1) & 3)) << 4);
  }

  for (int k0 = 0; k0 < D_DIM; k0 += 32) {
    __syncthreads();  // all waves done reading previous tile
#pragma unroll
    for (int q = 0; q < 2; q++) {
      GLOAD_LDS(xh + gaoff[q] + k0, (char*)Ah + ldsbase[q]);
      GLOAD_LDS(xl + gaoff[q] + k0, (char*)Al + ldsbase[q]);
      GLOAD_LDS(whT + gboff[q] + k0, (char*)Bh + ldsbase[q]);
      GLOAD_LDS(wlT + gboff[q] + k0, (char*)Bl + ldsbase[q]);
    }
    __syncthreads();  // compiler drains vmcnt before barrier -> data visible

    half8 a_h[4], a_l[4], b_h[4], b_l[4];
#pragma unroll
    for (int m = 0; m < 4; m++) {
      a_h[m] = *(const half8*)((const char*)Ah + aaddr[m]);
      a_l[m] = *(const half8*)((const char*)Al + aaddr[m]);
      b_h[m] = *(const half8*)((const char*)Bh + baddr[m]);
      b_l[m] = *(const half8*)((const char*)Bl + baddr[m]);
    }
#pragma unroll
    for (int m = 0; m < 4; m++)
#pragma unroll
      for (int n = 0; n < 4; n++) {
        acc[m][n] = __builtin_amdgcn_mfma_f32_16x16x32_f16(a_h[m], b_h[n],
                                                           acc[m][n], 0, 0, 0);
        acc[m][n] = __builtin_amdgcn_mfma_f32_16x16x32_f16(a_h[m], b_l[n],
                                                           acc[m][n], 0, 0, 0);
        acc[m][n] = __builtin_amdgcn_mfma_f32_16x16x32_f16(a_l[m], b_h[n],
                                                           acc[m][n], 0, 0, 0);
      }
  }

  // Epilogue: C/D layout col=lane&15, row=(lane>>4)*4+j  [m89-verified]
#pragma unroll
  for (int m = 0; m < 4; m++) {
    int rbase = row0 + wr * 64 + m * 16 + (lane >> 4) * 4;
#pragma unroll
    for (int n = 0; n < 4; n++) {
      int c = col0 + wc * 64 + n * 16 + (lane & 15);
#pragma unroll
      for (int j = 0; j < 4; j++) {
        h[(size_t)(rbase + j) * H_DIM + c] = acc[m][n][j];
      }
    }
  }
}

// ---------------------------------------------------------------------------
// Kernel 2: per 8 tokens: +b1, LayerNorm, exact GELU, logits = g @ W2 + b2,
// softmax, top-2 (lower-index tie-break), renorm weights.
// ---------------------------------------------------------------------------
__device__ __forceinline__ float gelu_exact(float v) {
  return 0.5f * v * (1.0f + erff(v * 0.70710678118654752f));
}

__global__ __launch_bounds__(256) void router_kernel(
    const float* __restrict__ hbuf, const float* __restrict__ b1,
    const float* __restrict__ gamma, const float* __restrict__ beta,
    const float* __restrict__ W2, const float* __restrict__ b2,
    float* __restrict__ out) {
  __shared__ float g[8][H_DIM];
  __shared__ float w2s[128][E_DIM];
  __shared__ float lg[8][E_DIM];

  const int t = threadIdx.x;
  const int tok0 = blockIdx.x * 8;

  const int tk = t >> 5;
  const int l32 = t & 31;
  float vals[32];
  {
    const float* hr = hbuf + (size_t)(tok0 + tk) * H_DIM;
    float s = 0.f, s2 = 0.f;
#pragma unroll
    for (int q = 0; q < 8; q++) {
      const int j = q * 128 + l32 * 4;
      float4 v = *(const float4*)(hr + j);
      float4 bb = *(const float4*)(b1 + j);
      v.x += bb.x; v.y += bb.y; v.z += bb.z; v.w += bb.w;
      vals[q * 4 + 0] = v.x; vals[q * 4 + 1] = v.y;
      vals[q * 4 + 2] = v.z; vals[q * 4 + 3] = v.w;
      s += v.x + v.y + v.z + v.w;
      s2 += v.x * v.x + v.y * v.y + v.z * v.z + v.w * v.w;
    }
#pragma unroll
    for (int off = 16; off; off >>= 1) {
      s += __shfl_xor(s, off, 32);
      s2 += __shfl_xor(s2, off, 32);
    }
    const float mean = s * (1.f / 1024.f);
    const float var = s2 * (1.f / 1024.f) - mean * mean;
    const float rstd = rsqrtf(var + 1e-5f);
#pragma unroll
    for (int q = 0; q < 8; q++) {
      const int j = q * 128 + l32 * 4;
      float4 gm = *(const float4*)(gamma + j);
      float4 bt = *(const float4*)(beta + j);
      float4 o;
      o.x = gelu_exact((vals[q * 4 + 0] - mean) * rstd * gm.x + bt.x);
      o.y = gelu_exact((vals[q * 4 + 1] - mean) * rstd * gm.y + bt.y);
      o.z = gelu_exact((vals[q * 4 + 2] - mean) * rstd * gm.z + bt.z);
      o.w = gelu_exact((vals[q * 4 + 3] - mean) * rstd * gm.w + bt.w);
      *(float4*)&g[tk][j] = o;
    }
  }

  {
    float* lgf = &lg[0][0];
    lgf[t] = b2[t & 63];
    lgf[t + 256] = b2[t & 63];
  }

  const int seg = t >> 6;
  const int cell = t & 63;
  const int tp = cell >> 4;
  const int e0 = (cell & 15) * 4;

  float acc0[4] = {0.f, 0.f, 0.f, 0.f};
  float acc1[4] = {0.f, 0.f, 0.f, 0.f};

  for (int c = 0; c < 8; c++) {
    __syncthreads();
#pragma unroll
    for (int q = 0; q < 8; q++) {
      const int idx = q * 1024 + t * 4;
      *(float4*)(&w2s[0][0] + idx) = *(const float4*)(W2 + c * 8192 + idx);
    }
    __syncthreads();
#pragma unroll
    for (int q = 0; q < 8; q++) {
      const int i = seg * 32 + q * 4;
      float4 g0 = *(const float4*)&g[2 * tp][c * 128 + i];
      float4 g1 = *(const float4*)&g[2 * tp + 1][c * 128 + i];
      float4 w0 = *(const float4*)&w2s[i + 0][e0];
      float4 w1 = *(const float4*)&w2s[i + 1][e0];
      float4 w2v = *(const float4*)&w2s[i + 2][e0];
      float4 w3 = *(const float4*)&w2s[i + 3][e0];
      acc0[0] = fmaf(g0.x, w0.x, acc0[0]); acc0[1] = fmaf(g0.x, w0.y, acc0[1]);
      acc0[2] = fmaf(g0.x, w0.z, acc0[2]); acc0[3] = fmaf(g0.x, w0.w, acc0[3]);
      acc0[0] = fmaf(g0.y, w1.x, acc0[0]); acc0[1] = fmaf(g0.y, w1.y, acc0[1]);
      acc0[2] = fmaf(g0.y, w1.z, acc0[2]); acc0[3] = fmaf(g0.y, w1.w, acc0[3]);
      acc0[0] = fmaf(g0.z, w2v.x, acc0[0]); acc0[1] = fmaf(g0.z, w2v.y, acc0[1]);
      acc0[2] = fmaf(g0.z, w2v.z, acc0[2]); acc0[3] = fmaf(g0.z, w2v.w, acc0[3]);
      acc0[0] = fmaf(g0.w, w3.x, acc0[0]); acc0[1] = fmaf(g0.w, w3.y, acc0[1]);
      acc0[2] = fmaf(g0.w, w3.z, acc0[2]); acc0[3] = fmaf(g0.w, w3.w, acc0[3]);
      acc1[0] = fmaf(g1.x, w0.x, acc1[0]); acc1[1] = fmaf(g1.x, w0.y, acc1[1]);
      acc1[2] = fmaf(g1.x, w0.z, acc1[2]); acc1[3] = fmaf(g1.x, w0.w, acc1[3]);
      acc1[0] = fmaf(g1.y, w1.x, acc1[0]); acc1[1] = fmaf(g1.y, w1.y, acc1[1]);
      acc1[2] = fmaf(g1.y, w1.z, acc1[2]); acc1[3] = fmaf(g1.y, w1.w, acc1[3]);
      acc1[0] = fmaf(g1.z, w2v.x, acc1[0]); acc1[1] = fmaf(g1.z, w2v.y, acc1[1]);
      acc1[2] = fmaf(g1.z, w2v.z, acc1[2]); acc1[3] = fmaf(g1.z, w2v.w, acc1[3]);
      acc1[0] = fmaf(g1.w, w3.x, acc1[0]); acc1[1] = fmaf(g1.w, w3.y, acc1[1]);
      acc1[2] = fmaf(g1.w, w3.z, acc1[2]); acc1[3] = fmaf(g1.w, w3.w, acc1[3]);
    }
  }
#pragma unroll
  for (int j = 0; j < 4; j++) {
    atomicAdd(&lg[2 * tp][e0 + j], acc0[j]);
    atomicAdd(&lg[2 * tp + 1][e0 + j], acc1[j]);
  }
  __syncthreads();

  float* out_idx = out;
  float* out_w = out + 32768;
  float* out_logits = out + 65536;

  const int wv = t >> 6;
  const int lane = t & 63;
#pragma unroll
  for (int tt = 0; tt < 2; tt++) {
    const int tok = wv * 2 + tt;
    const int n = tok0 + tok;
    const float L = lg[tok][lane];
    float m = L;
#pragma unroll
    for (int off = 32; off; off >>= 1) m = fmaxf(m, __shfl_xor(m, off));
    const float ex = expf(L - m);
    float sum = ex;
#pragma unroll
    for (int off = 32; off; off >>= 1) sum += __shfl_xor(sum, off);
    const float p = ex / sum;

    float v1 = p; int i1 = lane;
#pragma unroll
    for (int off = 32; off; off >>= 1) {
      float ov = __shfl_xor(v1, off);
      int oi = __shfl_xor(i1, off);
      if (ov > v1 || (ov == v1 && oi < i1)) { v1 = ov; i1 = oi; }
    }
    float v2 = (lane == i1) ? -1.f : p; int i2 = lane;
#pragma unroll
    for (int off = 32; off; off >>= 1) {
      float ov = __shfl_xor(v2, off);
      int oi = __shfl_xor(i2, off);
      if (ov > v2 || (ov == v2 && oi < i2)) { v2 = ov; i2 = oi; }
    }

    out_logits[(size_t)n * 64 + lane] = L;
    if (lane == 0) {
      const float dn = v1 + v2 + 1e-9f;
      out_idx[n * 2 + 0] = (float)i1;
      out_idx[n * 2 + 1] = (float)i2;
      out_w[n * 2 + 0] = v1 / dn;
      out_w[n * 2 + 1] = v2 / dn;
    }
  }
}

extern "C" void kernel_launch(void* const* d_in, const int* in_sizes, int n_in,
                              void* d_out, int out_size, void* d_ws, size_t ws_size,
                              hipStream_t stream) {
  const float* x = (const float*)d_in[0];
  const float* W1 = (const float*)d_in[1];
  const float* b1 = (const float*)d_in[2];
  const float* gamma = (const float*)d_in[3];
  const float* beta = (const float*)d_in[4];
  const float* W2 = (const float*)d_in[5];
  const float* b2 = (const float*)d_in[6];
  float* out = (float*)d_out;

  char* ws = (char*)d_ws;
  _Float16* xh = (_Float16*)ws;                    // 64 MiB
  _Float16* xl = (_Float16*)(ws + 67108864);       // 64 MiB
  _Float16* whT = (_Float16*)(ws + 134217728);     // 4 MiB
  _Float16* wlT = (_Float16*)(ws + 138412032);     // 4 MiB
  float* hbuf = (float*)(ws + 142606336);          // 64 MiB  (total 200 MiB)

  split_x_kernel<<<N_TOK * D_DIM / (8 * 256), 256, 0, stream>>>(x, xh, xl);
  splitT_w1_kernel<<<dim3(D_DIM / 64, H_DIM / 64), 256, 0, stream>>>(W1, whT, wlT);

  gemm1_mfma_kernel<<<dim3(H_DIM / 128, N_TOK / 128), 256, 0, stream>>>(
      xh, xl, whT, wlT, hbuf);

  router_kernel<<<N_TOK / 8, 256, 0, stream>>>(hbuf, b1, gamma, beta, W2, b2, out);
}

// Round 3
// 326.249 us; speedup vs baseline: 2.7625x; 1.2136x over previous
//
#include <hip/hip_runtime.h>
#include <hip/hip_bf16.h>
#include <cmath>

#define N_TOK 16384
#define D_DIM 2048
#define H_DIM 1024
#define E_DIM 64

typedef _Float16 half8 __attribute__((ext_vector_type(8)));
typedef float floatx4 __attribute__((ext_vector_type(4)));

#define GLOAD_LDS(gp, lp)                                                      \
  __builtin_amdgcn_global_load_lds(                                            \
      (const __attribute__((address_space(1))) unsigned int*)(gp),             \
      (__attribute__((address_space(3))) unsigned int*)(lp), 16, 0, 0)

// ---------------------------------------------------------------------------
// Split x (fp32) into hi/lo f16 arrays. 8 elems/thread.
// ---------------------------------------------------------------------------
__global__ __launch_bounds__(256) void split_x_kernel(
    const float* __restrict__ x, _Float16* __restrict__ xh,
    _Float16* __restrict__ xl) {
  size_t i = ((size_t)blockIdx.x * 256 + threadIdx.x) * 8;
  float4 v0 = *(const float4*)(x + i);
  float4 v1 = *(const float4*)(x + i + 4);
  float vs[8] = {v0.x, v0.y, v0.z, v0.w, v1.x, v1.y, v1.z, v1.w};
  half8 hh, ll;
#pragma unroll
  for (int j = 0; j < 8; j++) {
    _Float16 hv = (_Float16)vs[j];
    hh[j] = hv;
    ll[j] = (_Float16)(vs[j] - (float)hv);
  }
  *(half8*)(xh + i) = hh;
  *(half8*)(xl + i) = ll;
}

// ---------------------------------------------------------------------------
// Transpose + split W1 [2048k][1024c] -> whT/wlT [1024c][2048k] f16.
// ---------------------------------------------------------------------------
__global__ __launch_bounds__(256) void splitT_w1_kernel(
    const float* __restrict__ W1, _Float16* __restrict__ whT,
    _Float16* __restrict__ wlT) {
  __shared__ float ls[64][65];
  const int k0 = blockIdx.x * 64;
  const int c0 = blockIdx.y * 64;
  const int t = threadIdx.x;
  const int tr = t >> 6;
  const int tc = t & 63;
#pragma unroll
  for (int i = 0; i < 16; i++) {
    int k = tr * 16 + i;
    ls[k][tc] = W1[(size_t)(k0 + k) * H_DIM + c0 + tc];
  }
  __syncthreads();
#pragma unroll
  for (int i = 0; i < 16; i++) {
    int c = tr * 16 + i;
    float v = ls[tc][c];
    _Float16 hv = (_Float16)v;
    _Float16 lv = (_Float16)(v - (float)hv);
    whT[(size_t)(c0 + c) * D_DIM + k0 + tc] = hv;
    wlT[(size_t)(c0 + c) * D_DIM + k0 + tc] = lv;
  }
}

// ---------------------------------------------------------------------------
// GEMM1 via f16 split MFMA, 256x256 tile, BK=32, 512 thr (8 waves 2Mx4N),
// double-buffered 128KB LDS, prefetch-before-compute (T3-minimal 2-phase),
// one barrier per K-tile, XOR slot-swizzle (pre-swizzled global source),
// setprio around MFMA clusters (T5), bijective XCD swizzle (T1).
// ---------------------------------------------------------------------------
__global__ __launch_bounds__(512, 2) void gemm1_mfma_kernel(
    const _Float16* __restrict__ xh, const _Float16* __restrict__ xl,
    const _Float16* __restrict__ whT, const _Float16* __restrict__ wlT,
    float* __restrict__ h) {
  extern __shared__ __align__(16) char smem[];  // 2 x 64KB: Ah|Al|Bh|Bl

  const int t = threadIdx.x;
  const int wave = t >> 6;
  const int lane = t & 63;

  // XCD-aware swizzle: 256 wgs, 8 XCDs -> each XCD gets 8 row-tiles x 4 col.
  const int bid = blockIdx.x;
  const int swz = (bid & 7) * 32 + (bid >> 3);
  const int by = swz >> 2, bx = swz & 3;
  const int row0 = by * 256, col0 = bx * 256;
  const int wr = wave >> 2, wc = wave & 3;  // 2 x 4 wave grid

  floatx4 acc[8][4];
#pragma unroll
  for (int m = 0; m < 8; m++)
#pragma unroll
    for (int n = 0; n < 4; n++) acc[m][n] = (floatx4){0.f, 0.f, 0.f, 0.f};

  // Staging: per 16KB array, 2 issues x 512 thr x 16B. LDS linear; XOR
  // slot-swizzle applied on the GLOBAL source address (rule 21).
  int ldsoff[2];
  size_t gaoff[2], gboff[2];
#pragma unroll
  for (int q = 0; q < 2; q++) {
    const int o = q * 8192 + t * 16;   // byte offset in array
    const int row = o >> 6;            // 64B per row (32 f16)
    const int ss = ((o >> 4) & 3) ^ ((row >> 1) & 3);
    ldsoff[q] = q * 8192 + wave * 1024;  // wave-uniform dest base
    gaoff[q] = (size_t)(row0 + row) * D_DIM + ss * 8;
    gboff[q] = (size_t)(col0 + row) * D_DIM + ss * 8;
  }

  // Fragment ds_read byte addresses (within 16KB array), matching swizzle.
  const int kg = lane >> 4;
  const int fr = lane & 15;
  int aaddr[8], baddr[4];
#pragma unroll
  for (int m = 0; m < 8; m++) {
    const int r = wr * 128 + m * 16 + fr;
    aaddr[m] = r * 64 + ((kg ^ ((r >> 1) & 3)) << 4);
  }
#pragma unroll
  for (int n = 0; n < 4; n++) {
    const int c = wc * 64 + n * 16 + fr;
    baddr[n] = c * 64 + ((kg ^ ((c >> 1) & 3)) << 4);
  }

#define STAGE(buf, kt)                                                         \
  do {                                                                         \
    const size_t kk = (size_t)(kt) * 32;                                       \
    char* lb = smem + (buf) * 65536;                                           \
    GLOAD_LDS(xh + gaoff[0] + kk, lb + ldsoff[0]);                             \
    GLOAD_LDS(xh + gaoff[1] + kk, lb + ldsoff[1]);                             \
    GLOAD_LDS(xl + gaoff[0] + kk, lb + 16384 + ldsoff[0]);                     \
    GLOAD_LDS(xl + gaoff[1] + kk, lb + 16384 + ldsoff[1]);                     \
    GLOAD_LDS(whT + gboff[0] + kk, lb + 32768 + ldsoff[0]);                    \
    GLOAD_LDS(whT + gboff[1] + kk, lb + 32768 + ldsoff[1]);                    \
    GLOAD_LDS(wlT + gboff[0] + kk, lb + 49152 + ldsoff[0]);                    \
    GLOAD_LDS(wlT + gboff[1] + kk, lb + 49152 + ldsoff[1]);                    \
  } while (0)

  STAGE(0, 0);
  __syncthreads();  // drain prologue loads

  int cur = 0;
#pragma unroll 1
  for (int kt = 0; kt < 64; ++kt) {
    if (kt < 63) STAGE(cur ^ 1, kt + 1);   // prefetch next tile (stays in
    __builtin_amdgcn_sched_barrier(0);     // flight across the compute)
    const char* pAh = smem + cur * 65536;
    const char* pAl = pAh + 16384;
    const char* pBh = pAh + 32768;
    const char* pBl = pAh + 49152;

    half8 bh[4], bl[4];
#pragma unroll
    for (int n = 0; n < 4; n++) {
      bh[n] = *(const half8*)(pBh + baddr[n]);
      bl[n] = *(const half8*)(pBl + baddr[n]);
    }
#pragma unroll
    for (int m = 0; m < 8; m++) {
      half8 ah = *(const half8*)(pAh + aaddr[m]);
      half8 al = *(const half8*)(pAl + aaddr[m]);
      __builtin_amdgcn_s_setprio(1);
#pragma unroll
      for (int n = 0; n < 4; n++) {
        acc[m][n] = __builtin_amdgcn_mfma_f32_16x16x32_f16(ah, bh[n],
                                                           acc[m][n], 0, 0, 0);
        acc[m][n] = __builtin_amdgcn_mfma_f32_16x16x32_f16(ah, bl[n],
                                                           acc[m][n], 0, 0, 0);
        acc[m][n] = __builtin_amdgcn_mfma_f32_16x16x32_f16(al, bh[n],
                                                           acc[m][n], 0, 0, 0);
      }
      __builtin_amdgcn_s_setprio(0);
    }
    __syncthreads();  // vmcnt(0)+lgkmcnt(0) drain: prefetch had whole compute
    cur ^= 1;
  }
#undef STAGE

  // Epilogue: C/D layout col=lane&15, row=(lane>>4)*4+j  [m89-verified]
  const int rj = (lane >> 4) * 4;
#pragma unroll
  for (int m = 0; m < 8; m++) {
    const int rbase = row0 + wr * 128 + m * 16 + rj;
#pragma unroll
    for (int n = 0; n < 4; n++) {
      const int c = col0 + wc * 64 + n * 16 + fr;
#pragma unroll
      for (int j = 0; j < 4; j++) {
        h[(size_t)(rbase + j) * H_DIM + c] = acc[m][n][j];
      }
    }
  }
}

// ---------------------------------------------------------------------------
// Kernel 2: per 8 tokens: +b1, LayerNorm, exact GELU, logits = g @ W2 + b2,
// softmax, top-2 (lower-index tie-break), renorm weights.
// ---------------------------------------------------------------------------
__device__ __forceinline__ float gelu_exact(float v) {
  return 0.5f * v * (1.0f + erff(v * 0.70710678118654752f));
}

__global__ __launch_bounds__(256) void router_kernel(
    const float* __restrict__ hbuf, const float* __restrict__ b1,
    const float* __restrict__ gamma, const float* __restrict__ beta,
    const float* __restrict__ W2, const float* __restrict__ b2,
    float* __restrict__ out) {
  __shared__ float g[8][H_DIM];
  __shared__ float w2s[128][E_DIM];
  __shared__ float lg[8][E_DIM];

  const int t = threadIdx.x;
  const int tok0 = blockIdx.x * 8;

  const int tk = t >> 5;
  const int l32 = t & 31;
  float vals[32];
  {
    const float* hr = hbuf + (size_t)(tok0 + tk) * H_DIM;
    float s = 0.f, s2 = 0.f;
#pragma unroll
    for (int q = 0; q < 8; q++) {
      const int j = q * 128 + l32 * 4;
      float4 v = *(const float4*)(hr + j);
      float4 bb = *(const float4*)(b1 + j);
      v.x += bb.x; v.y += bb.y; v.z += bb.z; v.w += bb.w;
      vals[q * 4 + 0] = v.x; vals[q * 4 + 1] = v.y;
      vals[q * 4 + 2] = v.z; vals[q * 4 + 3] = v.w;
      s += v.x + v.y + v.z + v.w;
      s2 += v.x * v.x + v.y * v.y + v.z * v.z + v.w * v.w;
    }
#pragma unroll
    for (int off = 16; off; off >>= 1) {
      s += __shfl_xor(s, off, 32);
      s2 += __shfl_xor(s2, off, 32);
    }
    const float mean = s * (1.f / 1024.f);
    const float var = s2 * (1.f / 1024.f) - mean * mean;
    const float rstd = rsqrtf(var + 1e-5f);
#pragma unroll
    for (int q = 0; q < 8; q++) {
      const int j = q * 128 + l32 * 4;
      float4 gm = *(const float4*)(gamma + j);
      float4 bt = *(const float4*)(beta + j);
      float4 o;
      o.x = gelu_exact((vals[q * 4 + 0] - mean) * rstd * gm.x + bt.x);
      o.y = gelu_exact((vals[q * 4 + 1] - mean) * rstd * gm.y + bt.y);
      o.z = gelu_exact((vals[q * 4 + 2] - mean) * rstd * gm.z + bt.z);
      o.w = gelu_exact((vals[q * 4 + 3] - mean) * rstd * gm.w + bt.w);
      *(float4*)&g[tk][j] = o;
    }
  }

  {
    float* lgf = &lg[0][0];
    lgf[t] = b2[t & 63];
    lgf[t + 256] = b2[t & 63];
  }

  const int seg = t >> 6;
  const int cell = t & 63;
  const int tp = cell >> 4;
  const int e0 = (cell & 15) * 4;

  float acc0[4] = {0.f, 0.f, 0.f, 0.f};
  float acc1[4] = {0.f, 0.f, 0.f, 0.f};

  for (int c = 0; c < 8; c++) {
    __syncthreads();
#pragma unroll
    for (int q = 0; q < 8; q++) {
      const int idx = q * 1024 + t * 4;
      *(float4*)(&w2s[0][0] + idx) = *(const float4*)(W2 + c * 8192 + idx);
    }
    __syncthreads();
#pragma unroll
    for (int q = 0; q < 8; q++) {
      const int i = seg * 32 + q * 4;
      float4 g0 = *(const float4*)&g[2 * tp][c * 128 + i];
      float4 g1 = *(const float4*)&g[2 * tp + 1][c * 128 + i];
      float4 w0 = *(const float4*)&w2s[i + 0][e0];
      float4 w1 = *(const float4*)&w2s[i + 1][e0];
      float4 w2v = *(const float4*)&w2s[i + 2][e0];
      float4 w3 = *(const float4*)&w2s[i + 3][e0];
      acc0[0] = fmaf(g0.x, w0.x, acc0[0]); acc0[1] = fmaf(g0.x, w0.y, acc0[1]);
      acc0[2] = fmaf(g0.x, w0.z, acc0[2]); acc0[3] = fmaf(g0.x, w0.w, acc0[3]);
      acc0[0] = fmaf(g0.y, w1.x, acc0[0]); acc0[1] = fmaf(g0.y, w1.y, acc0[1]);
      acc0[2] = fmaf(g0.y, w1.z, acc0[2]); acc0[3] = fmaf(g0.y, w1.w, acc0[3]);
      acc0[0] = fmaf(g0.z, w2v.x, acc0[0]); acc0[1] = fmaf(g0.z, w2v.y, acc0[1]);
      acc0[2] = fmaf(g0.z, w2v.z, acc0[2]); acc0[3] = fmaf(g0.z, w2v.w, acc0[3]);
      acc0[0] = fmaf(g0.w, w3.x, acc0[0]); acc0[1] = fmaf(g0.w, w3.y, acc0[1]);
      acc0[2] = fmaf(g0.w, w3.z, acc0[2]); acc0[3] = fmaf(g0.w, w3.w, acc0[3]);
      acc1[0] = fmaf(g1.x, w0.x, acc1[0]); acc1[1] = fmaf(g1.x, w0.y, acc1[1]);
      acc1[2] = fmaf(g1.x, w0.z, acc1[2]); acc1[3] = fmaf(g1.x, w0.w, acc1[3]);
      acc1[0] = fmaf(g1.y, w1.x, acc1[0]); acc1[1] = fmaf(g1.y, w1.y, acc1[1]);
      acc1[2] = fmaf(g1.y, w1.z, acc1[2]); acc1[3] = fmaf(g1.y, w1.w, acc1[3]);
      acc1[0] = fmaf(g1.z, w2v.x, acc1[0]); acc1[1] = fmaf(g1.z, w2v.y, acc1[1]);
      acc1[2] = fmaf(g1.z, w2v.z, acc1[2]); acc1[3] = fmaf(g1.z, w2v.w, acc1[3]);
      acc1[0] = fmaf(g1.w, w3.x, acc1[0]); acc1[1] = fmaf(g1.w, w3.y, acc1[1]);
      acc1[2] = fmaf(g1.w, w3.z, acc1[2]); acc1[3] = fmaf(g1.w, w3.w, acc1[3]);
    }
  }
#pragma unroll
  for (int j = 0; j < 4; j++) {
    atomicAdd(&lg[2 * tp][e0 + j], acc0[j]);
    atomicAdd(&lg[2 * tp + 1][e0 + j], acc1[j]);
  }
  __syncthreads();

  float* out_idx = out;
  float* out_w = out + 32768;
  float* out_logits = out + 65536;

  const int wv = t >> 6;
  const int lane = t & 63;
#pragma unroll
  for (int tt = 0; tt < 2; tt++) {
    const int tok = wv * 2 + tt;
    const int n = tok0 + tok;
    const float L = lg[tok][lane];
    float m = L;
#pragma unroll
    for (int off = 32; off; off >>= 1) m = fmaxf(m, __shfl_xor(m, off));
    const float ex = expf(L - m);
    float sum = ex;
#pragma unroll
    for (int off = 32; off; off >>= 1) sum += __shfl_xor(sum, off);
    const float p = ex / sum;

    float v1 = p; int i1 = lane;
#pragma unroll
    for (int off = 32; off; off >>= 1) {
      float ov = __shfl_xor(v1, off);
      int oi = __shfl_xor(i1, off);
      if (ov > v1 || (ov == v1 && oi < i1)) { v1 = ov; i1 = oi; }
    }
    float v2 = (lane == i1) ? -1.f : p; int i2 = lane;
#pragma unroll
    for (int off = 32; off; off >>= 1) {
      float ov = __shfl_xor(v2, off);
      int oi = __shfl_xor(i2, off);
      if (ov > v2 || (ov == v2 && oi < i2)) { v2 = ov; i2 = oi; }
    }

    out_logits[(size_t)n * 64 + lane] = L;
    if (lane == 0) {
      const float dn = v1 + v2 + 1e-9f;
      out_idx[n * 2 + 0] = (float)i1;
      out_idx[n * 2 + 1] = (float)i2;
      out_w[n * 2 + 0] = v1 / dn;
      out_w[n * 2 + 1] = v2 / dn;
    }
  }
}

extern "C" void kernel_launch(void* const* d_in, const int* in_sizes, int n_in,
                              void* d_out, int out_size, void* d_ws, size_t ws_size,
                              hipStream_t stream) {
  const float* x = (const float*)d_in[0];
  const float* W1 = (const float*)d_in[1];
  const float* b1 = (const float*)d_in[2];
  const float* gamma = (const float*)d_in[3];
  const float* beta = (const float*)d_in[4];
  const float* W2 = (const float*)d_in[5];
  const float* b2 = (const float*)d_in[6];
  float* out = (float*)d_out;

  char* ws = (char*)d_ws;
  _Float16* xh = (_Float16*)ws;                    // 64 MiB
  _Float16* xl = (_Float16*)(ws + 67108864);       // 64 MiB
  _Float16* whT = (_Float16*)(ws + 134217728);     // 4 MiB
  _Float16* wlT = (_Float16*)(ws + 138412032);     // 4 MiB
  float* hbuf = (float*)(ws + 142606336);          // 64 MiB  (total 200 MiB)

  // Opt-in to 128KB dynamic LDS (host-side attr set, graph-capture safe).
  (void)hipFuncSetAttribute((const void*)gemm1_mfma_kernel,
                            hipFuncAttributeMaxDynamicSharedMemorySize,
                            131072);

  split_x_kernel<<<N_TOK * D_DIM / (8 * 256), 256, 0, stream>>>(x, xh, xl);
  splitT_w1_kernel<<<dim3(D_DIM / 64, H_DIM / 64), 256, 0, stream>>>(W1, whT, wlT);

  gemm1_mfma_kernel<<<256, 512, 131072, stream>>>(xh, xl, whT, wlT, hbuf);

  router_kernel<<<N_TOK / 8, 256, 0, stream>>>(hbuf, b1, gamma, beta, W2, b2, out);
}

// Round 4
// 290.820 us; speedup vs baseline: 3.0990x; 1.1218x over previous
//
#include <hip/hip_runtime.h>
#include <hip/hip_bf16.h>
#include <cmath>

#define N_TOK 16384
#define D_DIM 2048
#define H_DIM 1024
#define E_DIM 64

typedef _Float16 half8 __attribute__((ext_vector_type(8)));
typedef float floatx4 __attribute__((ext_vector_type(4)));

#define GLOAD_LDS(gp, lp)                                                      \
  __builtin_amdgcn_global_load_lds(                                            \
      (const __attribute__((address_space(1))) unsigned int*)(gp),             \
      (__attribute__((address_space(3))) unsigned int*)(lp), 16, 0, 0)

// ---------------------------------------------------------------------------
// Transpose + split W1 [2048k][1024c] -> whT/wlT [1024c][2048k] f16.
// ---------------------------------------------------------------------------
__global__ __launch_bounds__(256) void splitT_w1_kernel(
    const float* __restrict__ W1, _Float16* __restrict__ whT,
    _Float16* __restrict__ wlT) {
  __shared__ float ls[64][65];
  const int k0 = blockIdx.x * 64;
  const int c0 = blockIdx.y * 64;
  const int t = threadIdx.x;
  const int tr = t >> 6;
  const int tc = t & 63;
#pragma unroll
  for (int i = 0; i < 16; i++) {
    int k = tr * 16 + i;
    ls[k][tc] = W1[(size_t)(k0 + k) * H_DIM + c0 + tc];
  }
  __syncthreads();
#pragma unroll
  for (int i = 0; i < 16; i++) {
    int c = tr * 16 + i;
    float v = ls[tc][c];
    _Float16 hv = (_Float16)v;
    _Float16 lv = (_Float16)(v - (float)hv);
    whT[(size_t)(c0 + c) * D_DIM + k0 + tc] = hv;
    wlT[(size_t)(c0 + c) * D_DIM + k0 + tc] = lv;
  }
}

// ---------------------------------------------------------------------------
// GEMM1 via f16 split MFMA, 256x256 tile, BK=32, 512 thr (8 waves 2Mx4N),
// double-buffered 128KB LDS, prefetch-before-compute 2-phase.
// A (x fp32) is reg-staged: load fp32 early, split hi/lo f16 in-register
// AFTER the MFMA cluster (T14 issue-early/write-late), ds_write swizzled.
// B (whT/wlT pre-split f16) staged via global_load_lds, swizzled source.
// ---------------------------------------------------------------------------
__global__ __launch_bounds__(512, 2) void gemm1_mfma_kernel(
    const float* __restrict__ x,
    const _Float16* __restrict__ whT, const _Float16* __restrict__ wlT,
    float* __restrict__ h) {
  extern __shared__ __align__(16) char smem[];  // 2 x 64KB: Ah|Al|Bh|Bl

  const int t = threadIdx.x;
  const int wave = t >> 6;
  const int lane = t & 63;

  // XCD-aware swizzle: 256 wgs, 8 XCDs.
  const int bid = blockIdx.x;
  const int swz = (bid & 7) * 32 + (bid >> 3);
  const int by = swz >> 2, bx = swz & 3;
  const int row0 = by * 256, col0 = bx * 256;
  const int wr = wave >> 2, wc = wave & 3;  // 2 x 4 wave grid

  floatx4 acc[8][4];
#pragma unroll
  for (int m = 0; m < 8; m++)
#pragma unroll
    for (int n = 0; n < 4; n++) acc[m][n] = (floatx4){0.f, 0.f, 0.f, 0.f};

  // ---- A reg-staging mapping: unit u = (row, kslot) of 8 f32 ----
  int arow[2], aslot[2], awaddr[2];
  size_t gaoff[2];
#pragma unroll
  for (int q = 0; q < 2; q++) {
    const int u = q * 512 + t;
    arow[q] = u >> 2;
    aslot[q] = u & 3;
    awaddr[q] = arow[q] * 64 + ((aslot[q] ^ ((arow[q] >> 1) & 3)) << 4);
    gaoff[q] = (size_t)(row0 + arow[q]) * D_DIM + aslot[q] * 8;
  }

  // ---- B global_load_lds staging (swizzled global source, rule 21) ----
  int ldsoff[2];
  size_t gboff[2];
#pragma unroll
  for (int q = 0; q < 2; q++) {
    const int o = q * 8192 + t * 16;
    const int row = o >> 6;
    const int ss = ((o >> 4) & 3) ^ ((row >> 1) & 3);
    ldsoff[q] = q * 8192 + wave * 1024;
    gboff[q] = (size_t)(col0 + row) * D_DIM + ss * 8;
  }

  // Fragment ds_read byte addresses (within 16KB array), matching swizzle.
  const int kg = lane >> 4;
  const int fr = lane & 15;
  int aaddr[8], baddr[4];
#pragma unroll
  for (int m = 0; m < 8; m++) {
    const int r = wr * 128 + m * 16 + fr;
    aaddr[m] = r * 64 + ((kg ^ ((r >> 1) & 3)) << 4);
  }
#pragma unroll
  for (int n = 0; n < 4; n++) {
    const int c = wc * 64 + n * 16 + fr;
    baddr[n] = c * 64 + ((kg ^ ((c >> 1) & 3)) << 4);
  }

  float4 av[2][2];

#define LOAD_A(kt)                                                             \
  do {                                                                         \
    const size_t kk = (size_t)(kt) * 32;                                       \
    av[0][0] = *(const float4*)(x + gaoff[0] + kk);                            \
    av[0][1] = *(const float4*)(x + gaoff[0] + kk + 4);                        \
    av[1][0] = *(const float4*)(x + gaoff[1] + kk);                            \
    av[1][1] = *(const float4*)(x + gaoff[1] + kk + 4);                        \
  } while (0)

#define WRITE_A(buf)                                                           \
  do {                                                                         \
    char* lb = smem + (buf) * 65536;                                           \
    _Pragma("unroll") for (int q = 0; q < 2; q++) {                            \
      float vs[8] = {av[q][0].x, av[q][0].y, av[q][0].z, av[q][0].w,           \
                     av[q][1].x, av[q][1].y, av[q][1].z, av[q][1].w};          \
      half8 hh, ll;                                                            \
      _Pragma("unroll") for (int j = 0; j < 8; j++) {                          \
        _Float16 hv = (_Float16)vs[j];                                         \
        hh[j] = hv;                                                            \
        ll[j] = (_Float16)(vs[j] - (float)hv);                                 \
      }                                                                        \
      *(half8*)(lb + awaddr[q]) = hh;                                          \
      *(half8*)(lb + 16384 + awaddr[q]) = ll;                                  \
    }                                                                          \
  } while (0)

#define STAGE_B(buf, kt)                                                       \
  do {                                                                         \
    const size_t kk = (size_t)(kt) * 32;                                       \
    char* lb = smem + (buf) * 65536;                                           \
    GLOAD_LDS(whT + gboff[0] + kk, lb + 32768 + ldsoff[0]);                    \
    GLOAD_LDS(whT + gboff[1] + kk, lb + 32768 + ldsoff[1]);                    \
    GLOAD_LDS(wlT + gboff[0] + kk, lb + 49152 + ldsoff[0]);                    \
    GLOAD_LDS(wlT + gboff[1] + kk, lb + 49152 + ldsoff[1]);                    \
  } while (0)

  // Prologue: tile 0.
  LOAD_A(0);
  STAGE_B(0, 0);
  WRITE_A(0);
  __syncthreads();  // drains B gloads + orders A writes

  int cur = 0;
#pragma unroll 1
  for (int kt = 0; kt < 64; ++kt) {
    if (kt < 63) {
      LOAD_A(kt + 1);          // issue-early: latency hides under MFMA
      STAGE_B(cur ^ 1, kt + 1);
    }
    __builtin_amdgcn_sched_barrier(0);
    const char* pAh = smem + cur * 65536;
    const char* pAl = pAh + 16384;
    const char* pBh = pAh + 32768;
    const char* pBl = pAh + 49152;

    half8 bh[4], bl[4];
#pragma unroll
    for (int n = 0; n < 4; n++) {
      bh[n] = *(const half8*)(pBh + baddr[n]);
      bl[n] = *(const half8*)(pBl + baddr[n]);
    }
#pragma unroll
    for (int m = 0; m < 8; m++) {
      half8 ah = *(const half8*)(pAh + aaddr[m]);
      half8 al = *(const half8*)(pAl + aaddr[m]);
      __builtin_amdgcn_s_setprio(1);
#pragma unroll
      for (int n = 0; n < 4; n++) {
        acc[m][n] = __builtin_amdgcn_mfma_f32_16x16x32_f16(ah, bh[n],
                                                           acc[m][n], 0, 0, 0);
        acc[m][n] = __builtin_amdgcn_mfma_f32_16x16x32_f16(ah, bl[n],
                                                           acc[m][n], 0, 0, 0);
        acc[m][n] = __builtin_amdgcn_mfma_f32_16x16x32_f16(al, bh[n],
                                                           acc[m][n], 0, 0, 0);
      }
      __builtin_amdgcn_s_setprio(0);
    }
    if (kt < 63) WRITE_A(cur ^ 1);  // write-late: vmcnt waits only for A regs
    __syncthreads();
    cur ^= 1;
  }
#undef LOAD_A
#undef WRITE_A
#undef STAGE_B

  // Epilogue: C/D layout col=lane&15, row=(lane>>4)*4+j  [m89-verified]
  const int rj = (lane >> 4) * 4;
#pragma unroll
  for (int m = 0; m < 8; m++) {
    const int rbase = row0 + wr * 128 + m * 16 + rj;
#pragma unroll
    for (int n = 0; n < 4; n++) {
      const int c = col0 + wc * 64 + n * 16 + fr;
#pragma unroll
      for (int j = 0; j < 4; j++) {
        h[(size_t)(rbase + j) * H_DIM + c] = acc[m][n][j];
      }
    }
  }
}

// ---------------------------------------------------------------------------
// Kernel 2: per 8 tokens: +b1, LayerNorm, exact GELU, logits = g @ W2 + b2,
// softmax, top-2 (lower-index tie-break), renorm weights.
// ---------------------------------------------------------------------------
__device__ __forceinline__ float gelu_exact(float v) {
  return 0.5f * v * (1.0f + erff(v * 0.70710678118654752f));
}

__global__ __launch_bounds__(256) void router_kernel(
    const float* __restrict__ hbuf, const float* __restrict__ b1,
    const float* __restrict__ gamma, const float* __restrict__ beta,
    const float* __restrict__ W2, const float* __restrict__ b2,
    float* __restrict__ out) {
  __shared__ float g[8][H_DIM];
  __shared__ float w2s[128][E_DIM];
  __shared__ float lg[8][E_DIM];

  const int t = threadIdx.x;
  const int tok0 = blockIdx.x * 8;

  const int tk = t >> 5;
  const int l32 = t & 31;
  float vals[32];
  {
    const float* hr = hbuf + (size_t)(tok0 + tk) * H_DIM;
    float s = 0.f, s2 = 0.f;
#pragma unroll
    for (int q = 0; q < 8; q++) {
      const int j = q * 128 + l32 * 4;
      float4 v = *(const float4*)(hr + j);
      float4 bb = *(const float4*)(b1 + j);
      v.x += bb.x; v.y += bb.y; v.z += bb.z; v.w += bb.w;
      vals[q * 4 + 0] = v.x; vals[q * 4 + 1] = v.y;
      vals[q * 4 + 2] = v.z; vals[q * 4 + 3] = v.w;
      s += v.x + v.y + v.z + v.w;
      s2 += v.x * v.x + v.y * v.y + v.z * v.z + v.w * v.w;
    }
#pragma unroll
    for (int off = 16; off; off >>= 1) {
      s += __shfl_xor(s, off, 32);
      s2 += __shfl_xor(s2, off, 32);
    }
    const float mean = s * (1.f / 1024.f);
    const float var = s2 * (1.f / 1024.f) - mean * mean;
    const float rstd = rsqrtf(var + 1e-5f);
#pragma unroll
    for (int q = 0; q < 8; q++) {
      const int j = q * 128 + l32 * 4;
      float4 gm = *(const float4*)(gamma + j);
      float4 bt = *(const float4*)(beta + j);
      float4 o;
      o.x = gelu_exact((vals[q * 4 + 0] - mean) * rstd * gm.x + bt.x);
      o.y = gelu_exact((vals[q * 4 + 1] - mean) * rstd * gm.y + bt.y);
      o.z = gelu_exact((vals[q * 4 + 2] - mean) * rstd * gm.z + bt.z);
      o.w = gelu_exact((vals[q * 4 + 3] - mean) * rstd * gm.w + bt.w);
      *(float4*)&g[tk][j] = o;
    }
  }

  {
    float* lgf = &lg[0][0];
    lgf[t] = b2[t & 63];
    lgf[t + 256] = b2[t & 63];
  }

  const int seg = t >> 6;
  const int cell = t & 63;
  const int tp = cell >> 4;
  const int e0 = (cell & 15) * 4;

  float acc0[4] = {0.f, 0.f, 0.f, 0.f};
  float acc1[4] = {0.f, 0.f, 0.f, 0.f};

  for (int c = 0; c < 8; c++) {
    __syncthreads();
#pragma unroll
    for (int q = 0; q < 8; q++) {
      const int idx = q * 1024 + t * 4;
      *(float4*)(&w2s[0][0] + idx) = *(const float4*)(W2 + c * 8192 + idx);
    }
    __syncthreads();
#pragma unroll
    for (int q = 0; q < 8; q++) {
      const int i = seg * 32 + q * 4;
      float4 g0 = *(const float4*)&g[2 * tp][c * 128 + i];
      float4 g1 = *(const float4*)&g[2 * tp + 1][c * 128 + i];
      float4 w0 = *(const float4*)&w2s[i + 0][e0];
      float4 w1 = *(const float4*)&w2s[i + 1][e0];
      float4 w2v = *(const float4*)&w2s[i + 2][e0];
      float4 w3 = *(const float4*)&w2s[i + 3][e0];
      acc0[0] = fmaf(g0.x, w0.x, acc0[0]); acc0[1] = fmaf(g0.x, w0.y, acc0[1]);
      acc0[2] = fmaf(g0.x, w0.z, acc0[2]); acc0[3] = fmaf(g0.x, w0.w, acc0[3]);
      acc0[0] = fmaf(g0.y, w1.x, acc0[0]); acc0[1] = fmaf(g0.y, w1.y, acc0[1]);
      acc0[2] = fmaf(g0.y, w1.z, acc0[2]); acc0[3] = fmaf(g0.y, w1.w, acc0[3]);
      acc0[0] = fmaf(g0.z, w2v.x, acc0[0]); acc0[1] = fmaf(g0.z, w2v.y, acc0[1]);
      acc0[2] = fmaf(g0.z, w2v.z, acc0[2]); acc0[3] = fmaf(g0.z, w2v.w, acc0[3]);
      acc0[0] = fmaf(g0.w, w3.x, acc0[0]); acc0[1] = fmaf(g0.w, w3.y, acc0[1]);
      acc0[2] = fmaf(g0.w, w3.z, acc0[2]); acc0[3] = fmaf(g0.w, w3.w, acc0[3]);
      acc1[0] = fmaf(g1.x, w0.x, acc1[0]); acc1[1] = fmaf(g1.x, w0.y, acc1[1]);
      acc1[2] = fmaf(g1.x, w0.z, acc1[2]); acc1[3] = fmaf(g1.x, w0.w, acc1[3]);
      acc1[0] = fmaf(g1.y, w1.x, acc1[0]); acc1[1] = fmaf(g1.y, w1.y, acc1[1]);
      acc1[2] = fmaf(g1.y, w1.z, acc1[2]); acc1[3] = fmaf(g1.y, w1.w, acc1[3]);
      acc1[0] = fmaf(g1.z, w2v.x, acc1[0]); acc1[1] = fmaf(g1.z, w2v.y, acc1[1]);
      acc1[2] = fmaf(g1.z, w2v.z, acc1[2]); acc1[3] = fmaf(g1.z, w2v.w, acc1[3]);
      acc1[0] = fmaf(g1.w, w3.x, acc1[0]); acc1[1] = fmaf(g1.w, w3.y, acc1[1]);
      acc1[2] = fmaf(g1.w, w3.z, acc1[2]); acc1[3] = fmaf(g1.w, w3.w, acc1[3]);
    }
  }
#pragma unroll
  for (int j = 0; j < 4; j++) {
    atomicAdd(&lg[2 * tp][e0 + j], acc0[j]);
    atomicAdd(&lg[2 * tp + 1][e0 + j], acc1[j]);
  }
  __syncthreads();

  float* out_idx = out;
  float* out_w = out + 32768;
  float* out_logits = out + 65536;

  const int wv = t >> 6;
  const int lane = t & 63;
#pragma unroll
  for (int tt = 0; tt < 2; tt++) {
    const int tok = wv * 2 + tt;
    const int n = tok0 + tok;
    const float L = lg[tok][lane];
    float m = L;
#pragma unroll
    for (int off = 32; off; off >>= 1) m = fmaxf(m, __shfl_xor(m, off));
    const float ex = expf(L - m);
    float sum = ex;
#pragma unroll
    for (int off = 32; off; off >>= 1) sum += __shfl_xor(sum, off);
    const float p = ex / sum;

    float v1 = p; int i1 = lane;
#pragma unroll
    for (int off = 32; off; off >>= 1) {
      float ov = __shfl_xor(v1, off);
      int oi = __shfl_xor(i1, off);
      if (ov > v1 || (ov == v1 && oi < i1)) { v1 = ov; i1 = oi; }
    }
    float v2 = (lane == i1) ? -1.f : p; int i2 = lane;
#pragma unroll
    for (int off = 32; off; off >>= 1) {
      float ov = __shfl_xor(v2, off);
      int oi = __shfl_xor(i2, off);
      if (ov > v2 || (ov == v2 && oi < i2)) { v2 = ov; i2 = oi; }
    }

    out_logits[(size_t)n * 64 + lane] = L;
    if (lane == 0) {
      const float dn = v1 + v2 + 1e-9f;
      out_idx[n * 2 + 0] = (float)i1;
      out_idx[n * 2 + 1] = (float)i2;
      out_w[n * 2 + 0] = v1 / dn;
      out_w[n * 2 + 1] = v2 / dn;
    }
  }
}

extern "C" void kernel_launch(void* const* d_in, const int* in_sizes, int n_in,
                              void* d_out, int out_size, void* d_ws, size_t ws_size,
                              hipStream_t stream) {
  const float* x = (const float*)d_in[0];
  const float* W1 = (const float*)d_in[1];
  const float* b1 = (const float*)d_in[2];
  const float* gamma = (const float*)d_in[3];
  const float* beta = (const float*)d_in[4];
  const float* W2 = (const float*)d_in[5];
  const float* b2 = (const float*)d_in[6];
  float* out = (float*)d_out;

  char* ws = (char*)d_ws;
  _Float16* whT = (_Float16*)ws;                 // 4 MiB
  _Float16* wlT = (_Float16*)(ws + 4194304);     // 4 MiB
  float* hbuf = (float*)(ws + 8388608);          // 64 MiB (total 72 MiB)

  (void)hipFuncSetAttribute((const void*)gemm1_mfma_kernel,
                            hipFuncAttributeMaxDynamicSharedMemorySize,
                            131072);

  splitT_w1_kernel<<<dim3(D_DIM / 64, H_DIM / 64), 256, 0, stream>>>(W1, whT, wlT);

  gemm1_mfma_kernel<<<256, 512, 131072, stream>>>(x, whT, wlT, hbuf);

  router_kernel<<<N_TOK / 8, 256, 0, stream>>>(hbuf, b1, gamma, beta, W2, b2, out);
}